// Round 9
// baseline (307.192 us; speedup 1.0000x reference)
//
#include <hip/hip_runtime.h>
#include <hip/hip_bf16.h>

#define NB 2
#define TT 16
#define SS 196
#define DD 768
#define NHEADS 12
#define HD 64
#define TOK (NB*TT*SS)        // 6272 tokens
#define QPN (TT*SS)           // 3136 queries per batch
#define KPN (TT*(SS/2))       // 1568 keys per batch

typedef _Float16 f16;
typedef _Float16 f16x4 __attribute__((ext_vector_type(4)));
typedef _Float16 f16x8 __attribute__((ext_vector_type(8)));
typedef float    f32x4 __attribute__((ext_vector_type(4)));
typedef unsigned int u32;

static __device__ __forceinline__ u32 pk16(float a, float b) {
    return __builtin_bit_cast(u32, __builtin_amdgcn_cvt_pkrtz(a, b));
}

// ---------------- cast fp32 -> fp16 ----------------
__global__ void cast_f32_to_f16(const float* __restrict__ in, f16* __restrict__ out, int n4) {
    int i = blockIdx.x * blockDim.x + threadIdx.x;
    if (i < n4) {
        float4 v = reinterpret_cast<const float4*>(in)[i];
        f16x4 h; h[0] = (f16)v.x; h[1] = (f16)v.y; h[2] = (f16)v.z; h[3] = (f16)v.w;
        reinterpret_cast<f16x4*>(out)[i] = h;
    }
}

// ---------------- transpose + cast: in fp32 [R][C] -> out f16 [C][R] ----------------
__global__ void transpose_cast(const float* __restrict__ in, f16* __restrict__ out, int R, int C) {
    __shared__ float tile[32][33];
    int c0 = blockIdx.x * 32, r0 = blockIdx.y * 32;
    int tx = threadIdx.x & 31, ty = threadIdx.x >> 5;   // 32 x 8
#pragma unroll
    for (int j = 0; j < 4; j++)
        tile[ty + 8*j][tx] = in[(size_t)(r0 + ty + 8*j) * C + c0 + tx];
    __syncthreads();
#pragma unroll
    for (int j = 0; j < 4; j++)
        out[(size_t)(c0 + ty + 8*j) * R + r0 + tx] = (f16)tile[tx][ty + 8*j];
}

// ---------------- f16 MFMA GEMM: C[M][N] = A[M][K] @ Bt[N][K]^T ----------------
// EPI 0: scatter q(f16, pre-scaled 0.125), k(f16 row-major), v(f16 TRANSPOSED per head)
// EPI 1: + bias, write fp32 to d_out
template<int EPI>
__launch_bounds__(256, 2)
__global__ void gemm_f16(const f16* __restrict__ A, const f16* __restrict__ Bt,
                         int M, int N, int K,
                         f16* __restrict__ q16, f16* __restrict__ k16,
                         f16* __restrict__ vt16,
                         const float* __restrict__ bias, float* __restrict__ outf) {
    __shared__ f16 As[128 * 40];   // 128 rows x 32 k, padded to 40 f16
    __shared__ f16 Bs[128 * 40];
    int tid  = threadIdx.x;
    int lane = tid & 63, w = tid >> 6;
    int wm = w >> 1, wn = w & 1;                 // 2x2 waves, each 64x64
    int l15 = lane & 15, l4 = lane >> 4;
    int mBase = blockIdx.y * 128, nBase = blockIdx.x * 128;
    int r0 = tid >> 2, s0 = tid & 3;             // staging: row, 8-f16 segment

    f32x4 acc[4][4] = {};

    const int KT = K / 32;
    for (int kt = 0; kt < KT; kt++) {
        int k0 = kt * 32;
        *(f16x8*)&As[r0*40 + s0*8]        = *(const f16x8*)&A [(size_t)(mBase + r0     ) * K + k0 + s0*8];
        *(f16x8*)&As[(r0+64)*40 + s0*8]   = *(const f16x8*)&A [(size_t)(mBase + r0 + 64) * K + k0 + s0*8];
        *(f16x8*)&Bs[r0*40 + s0*8]        = *(const f16x8*)&Bt[(size_t)(nBase + r0     ) * K + k0 + s0*8];
        *(f16x8*)&Bs[(r0+64)*40 + s0*8]   = *(const f16x8*)&Bt[(size_t)(nBase + r0 + 64) * K + k0 + s0*8];
        __syncthreads();
        f16x8 af[4], bf[4];
#pragma unroll
        for (int i = 0; i < 4; i++) {
            af[i] = *(const f16x8*)&As[(wm*64 + i*16 + l15)*40 + l4*8];
            bf[i] = *(const f16x8*)&Bs[(wn*64 + i*16 + l15)*40 + l4*8];
        }
#pragma unroll
        for (int i = 0; i < 4; i++)
#pragma unroll
            for (int j = 0; j < 4; j++)
                acc[i][j] = __builtin_amdgcn_mfma_f32_16x16x32_f16(af[i], bf[j], acc[i][j], 0, 0, 0);
        __syncthreads();
    }

    int rbase2 = mBase + wm*64;
    int cbase2 = nBase + wn*64;
#pragma unroll
    for (int i = 0; i < 4; i++) {
#pragma unroll
        for (int j = 0; j < 4; j++) {
            int col = cbase2 + j*16 + l15;
#pragma unroll
            for (int r = 0; r < 4; r++) {
                int row = rbase2 + i*16 + l4*4 + r;
                float val = acc[i][j][r];
                if constexpr (EPI == 0) {
                    if (col < 768) {
                        q16[(size_t)row * 768 + col] = (f16)(val * 0.125f);  // fold attn SCALE
                    } else {
                        int n = row / QPN; int rem = row - n*QPN;
                        int t = rem / SS;  int s   = rem - t*SS;
                        if (!(s & 1)) {
                            int kb = t*(SS/2) + (s >> 1);                    // key idx within batch
                            if (col < 1536) {
                                k16[(size_t)(n*KPN + kb) * 768 + (col - 768)] = (f16)val;
                            } else {
                                int c = col - 1536; int hh = c >> 6, dd = c & 63;
                                vt16[((size_t)(n*NHEADS + hh)*64 + dd) * KPN + kb] = (f16)val;
                            }
                        }
                    }
                } else {
                    outf[(size_t)row * 768 + col] = val + bias[col];
                }
            }
        }
    }
}

// ---------------- MFMA flash attention (16x16x32, KVBLK=64 + 32-key tail) ----------
// Block: 256 thr = 4 waves, each wave owns 16 q-rows. Grid (49, 24).
// All LDS rows 68 f16 = 136B: bank rotation 2*row mod 32 has period 16 -> b128
// reads across 16 rows are conflict-free. Swapped QK^T: S[key][q]; P via per-wave
// LDS round-trip; PV: O[d][q] = mfma(Vt, P). Defer-max (T13, THR=8).
__launch_bounds__(256, 2)
__global__ void attn_mfma(const f16* __restrict__ q16, const f16* __restrict__ k16,
                          const f16* __restrict__ vt16, f16* __restrict__ o16) {
    int tid = threadIdx.x;
    int lane = tid & 63, w = tid >> 6;
    int qt = blockIdx.x, nh = blockIdx.y;
    int n = nh / NHEADS, h = nh - n*NHEADS;
    int l15 = lane & 15, l4 = lane >> 4;

    __shared__ f16 Klds[64 * 68];       // 64 keys x 64 d (+4 pad)
    __shared__ f16 Vtlds[64 * 68];      // 64 d x 64 keys (+4 pad)
    __shared__ f16 Plds[4][16 * 68];    // per-wave: 16 q x 64 keys (+4 pad)

    // main staging: rows srow and srow+32, 8 segs of 8 f16 (16B) per row
    int srow = tid >> 3, sseg = tid & 7;
    const f16* kgb = k16 + (size_t)n * KPN * 768 + h * 64;
    const f16* vgb = vt16 + ((size_t)nh * 64 + srow) * KPN;   // V^T row d=srow
    // tail staging coords (V: 64 rows x 32 keys)
    int tvd = tid >> 2, tvs = tid & 3;
    const f16* vgb_tail = vt16 + ((size_t)nh * 64 + tvd) * KPN;

    int qglob = n*QPN + qt*64 + w*16 + l15;
    const f16* qrow = q16 + (size_t)qglob * 768 + h*64;
    f16x8 qf0 = *(const f16x8*)&qrow[l4*8];        // B-frag: col=q=l15, k=d=l4*8+i
    f16x8 qf1 = *(const f16x8*)&qrow[32 + l4*8];   // d = 32+l4*8+i

    f32x4 acc[4] = {};                  // acc[c][r] -> O[d=c*16+l4*4+r][q=l15]
    float M = -INFINITY, L = 0.f;

    // preload tile 0
    f16x8 stKa = *(const f16x8*)&kgb[(size_t)srow * 768 + sseg*8];
    f16x8 stKb = *(const f16x8*)&kgb[(size_t)(srow+32) * 768 + sseg*8];
    f16x8 stVa = *(const f16x8*)&vgb[sseg*8];
    f16x8 stVb = *(const f16x8*)&vgb[(size_t)32*KPN + sseg*8];

    for (int t = 0; t < 24; t++) {
        __syncthreads();   // prev tile reads done
        *(f16x8*)&Klds [srow*68 + sseg*8]      = stKa;
        *(f16x8*)&Klds [(srow+32)*68 + sseg*8] = stKb;
        *(f16x8*)&Vtlds[srow*68 + sseg*8]      = stVa;
        *(f16x8*)&Vtlds[(srow+32)*68 + sseg*8] = stVb;
        __syncthreads();   // tile t visible

        if (t < 23) {      // prefetch next 64-key tile
            int kb = (t + 1) * 64;
            stKa = *(const f16x8*)&kgb[(size_t)(kb + srow) * 768 + sseg*8];
            stKb = *(const f16x8*)&kgb[(size_t)(kb + srow + 32) * 768 + sseg*8];
            stVa = *(const f16x8*)&vgb[kb + sseg*8];
            stVb = *(const f16x8*)&vgb[(size_t)32*KPN + kb + sseg*8];
        } else {           // prefetch 32-key tail
            stKa = *(const f16x8*)&kgb[(size_t)(1536 + srow) * 768 + sseg*8];
            stVa = *(const f16x8*)&vgb_tail[1536 + tvs*8];
        }

        // ---- QK^T: S[kh][r] = S[key = kh*16+l4*4+r][q = l15]
        f32x4 S[4];
#pragma unroll
        for (int kh = 0; kh < 4; kh++) {
            const f16* kr = &Klds[(kh*16 + l15)*68];
            f16x8 ka0 = *(const f16x8*)&kr[l4*8];
            f16x8 ka1 = *(const f16x8*)&kr[32 + l4*8];
            f32x4 s = {};
            s = __builtin_amdgcn_mfma_f32_16x16x32_f16(ka0, qf0, s, 0, 0, 0);
            s = __builtin_amdgcn_mfma_f32_16x16x32_f16(ka1, qf1, s, 0, 0, 0);
            S[kh] = s;
        }

        // ---- online softmax (q = l15; reduce over l4 group via shfl 16/32)
        float tm = -INFINITY;
#pragma unroll
        for (int kh = 0; kh < 4; kh++)
            tm = fmaxf(tm, fmaxf(fmaxf(S[kh][0], S[kh][1]), fmaxf(S[kh][2], S[kh][3])));
        tm = fmaxf(tm, __shfl_xor(tm, 16));
        tm = fmaxf(tm, __shfl_xor(tm, 32));
        if (!__all(tm - M <= 8.f)) {        // defer-max: rescale only on real growth
            float Mnew = fmaxf(M, tm);
            float cor = __expf(M - Mnew);   // first tile: exp(-inf)=0
            L *= cor;
#pragma unroll
            for (int c = 0; c < 4; c++) acc[c] *= cor;
            M = Mnew;
        }
        float ls = 0.f;
        f16* pw = &Plds[w][l15*68];
#pragma unroll
        for (int kh = 0; kh < 4; kh++) {
            float p0 = __expf(S[kh][0] - M), p1 = __expf(S[kh][1] - M);
            float p2 = __expf(S[kh][2] - M), p3 = __expf(S[kh][3] - M);
            ls += (p0 + p1) + (p2 + p3);
            uint2 pk2; pk2.x = pk16(p0, p1); pk2.y = pk16(p2, p3);
            *(uint2*)&pw[kh*16 + l4*4] = pk2;     // keys kh*16 + l4*4 + 0..3
        }
        ls += __shfl_xor(ls, 16);
        ls += __shfl_xor(ls, 32);
        L += ls;

        // ---- PV: O[d][q] += Vt[d][k] * P[q][k], two 32-key slices
#pragma unroll
        for (int ks = 0; ks < 2; ks++) {
            f16x8 pf = *(const f16x8*)&Plds[w][l15*68 + ks*32 + l4*8];
#pragma unroll
            for (int c = 0; c < 4; c++) {
                f16x8 vf = *(const f16x8*)&Vtlds[(c*16 + l15)*68 + ks*32 + l4*8];
                acc[c] = __builtin_amdgcn_mfma_f32_16x16x32_f16(vf, pf, acc[c], 0, 0, 0);
            }
        }
    }

    // ---- tail: 32 keys at kb=1536 ----
    __syncthreads();
    *(f16x8*)&Klds [srow*68 + sseg*8] = stKa;      // 32 key-rows
    *(f16x8*)&Vtlds[tvd*68 + tvs*8]   = stVa;      // 64 d-rows x 32 keys
    __syncthreads();
    {
        f32x4 S[2];
#pragma unroll
        for (int kh = 0; kh < 2; kh++) {
            const f16* kr = &Klds[(kh*16 + l15)*68];
            f16x8 ka0 = *(const f16x8*)&kr[l4*8];
            f16x8 ka1 = *(const f16x8*)&kr[32 + l4*8];
            f32x4 s = {};
            s = __builtin_amdgcn_mfma_f32_16x16x32_f16(ka0, qf0, s, 0, 0, 0);
            s = __builtin_amdgcn_mfma_f32_16x16x32_f16(ka1, qf1, s, 0, 0, 0);
            S[kh] = s;
        }
        float tm = -INFINITY;
#pragma unroll
        for (int kh = 0; kh < 2; kh++)
            tm = fmaxf(tm, fmaxf(fmaxf(S[kh][0], S[kh][1]), fmaxf(S[kh][2], S[kh][3])));
        tm = fmaxf(tm, __shfl_xor(tm, 16));
        tm = fmaxf(tm, __shfl_xor(tm, 32));
        if (!__all(tm - M <= 8.f)) {
            float Mnew = fmaxf(M, tm);
            float cor = __expf(M - Mnew);
            L *= cor;
#pragma unroll
            for (int c = 0; c < 4; c++) acc[c] *= cor;
            M = Mnew;
        }
        float ls = 0.f;
        f16* pw = &Plds[w][l15*68];
#pragma unroll
        for (int kh = 0; kh < 2; kh++) {
            float p0 = __expf(S[kh][0] - M), p1 = __expf(S[kh][1] - M);
            float p2 = __expf(S[kh][2] - M), p3 = __expf(S[kh][3] - M);
            ls += (p0 + p1) + (p2 + p3);
            uint2 pk2; pk2.x = pk16(p0, p1); pk2.y = pk16(p2, p3);
            *(uint2*)&pw[kh*16 + l4*4] = pk2;
        }
        ls += __shfl_xor(ls, 16);
        ls += __shfl_xor(ls, 32);
        L += ls;

        f16x8 pf = *(const f16x8*)&Plds[w][l15*68 + l4*8];
#pragma unroll
        for (int c = 0; c < 4; c++) {
            f16x8 vf = *(const f16x8*)&Vtlds[(c*16 + l15)*68 + l4*8];
            acc[c] = __builtin_amdgcn_mfma_f32_16x16x32_f16(vf, pf, acc[c], 0, 0, 0);
        }
    }

    // ---- epilogue: O[q][d] = acc / L
    float inv = 1.f / L;
    f16* orow = o16 + (size_t)qglob * 768 + h*64;
#pragma unroll
    for (int c = 0; c < 4; c++) {
        uint2 o2;
        o2.x = pk16(acc[c][0]*inv, acc[c][1]*inv);
        o2.y = pk16(acc[c][2]*inv, acc[c][3]*inv);
        *(uint2*)&orow[c*16 + l4*4] = o2;
    }
}

extern "C" void kernel_launch(void* const* d_in, const int* in_sizes, int n_in,
                              void* d_out, int out_size, void* d_ws, size_t ws_size,
                              hipStream_t stream) {
    const float* x      = (const float*)d_in[0];
    const float* W_qkv  = (const float*)d_in[1];
    const float* W_proj = (const float*)d_in[2];
    const float* b_proj = (const float*)d_in[3];
    float* out = (float*)d_out;

    char* ws = (char*)d_ws;
    size_t off = 0;
    auto alloc = [&](size_t bytes) { void* p = ws + off; off += (bytes + 255) & ~255ULL; return p; };
    f16* x16    = (f16*)alloc((size_t)TOK * DD * 2);
    f16* WqkvT  = (f16*)alloc((size_t)2304 * 768 * 2);
    f16* WprojT = (f16*)alloc((size_t)768 * 768 * 2);
    f16* q16    = (f16*)alloc((size_t)TOK * DD * 2);
    f16* k16    = (f16*)alloc((size_t)NB * KPN * DD * 2);
    f16* vt16   = (f16*)alloc((size_t)NB * NHEADS * HD * KPN * 2);
    f16* o16    = (f16*)alloc((size_t)TOK * DD * 2);
    (void)ws_size; (void)in_sizes; (void)n_in; (void)out_size;

    cast_f32_to_f16<<<(TOK*DD/4 + 255)/256, 256, 0, stream>>>(x, x16, TOK*DD/4);
    transpose_cast<<<dim3(2304/32, 768/32), 256, 0, stream>>>(W_qkv, WqkvT, 768, 2304);
    transpose_cast<<<dim3(768/32, 768/32), 256, 0, stream>>>(W_proj, WprojT, 768, 768);
    gemm_f16<0><<<dim3(2304/128, 6272/128), 256, 0, stream>>>(
        x16, WqkvT, TOK, 2304, 768, q16, k16, vt16, nullptr, nullptr);
    attn_mfma<<<dim3(49, 24), 256, 0, stream>>>(q16, k16, vt16, o16);
    gemm_f16<1><<<dim3(768/128, 6272/128), 256, 0, stream>>>(
        o16, WprojT, TOK, 768, 768, nullptr, nullptr, nullptr, b_proj, out);
}

// Round 10
// 224.045 us; speedup vs baseline: 1.3711x; 1.3711x over previous
//
#include <hip/hip_runtime.h>
#include <hip/hip_bf16.h>

#define NB 2
#define TT 16
#define SS 196
#define DD 768
#define NHEADS 12
#define HD 64
#define TOK (NB*TT*SS)        // 6272 tokens
#define QPN (TT*SS)           // 3136 queries per batch
#define KPN (TT*(SS/2))       // 1568 keys per batch
#define LSTR 72               // LDS row stride in f16: 144B, 16B-aligned, 2-way-min banks

typedef _Float16 f16;
typedef _Float16 f16x4 __attribute__((ext_vector_type(4)));
typedef _Float16 f16x8 __attribute__((ext_vector_type(8)));
typedef float    f32x4 __attribute__((ext_vector_type(4)));
typedef unsigned int u32;

static __device__ __forceinline__ u32 pk16(float a, float b) {
    return __builtin_bit_cast(u32, __builtin_amdgcn_cvt_pkrtz(a, b));
}

// ---------------- cast fp32 -> fp16 ----------------
__global__ void cast_f32_to_f16(const float* __restrict__ in, f16* __restrict__ out, int n4) {
    int i = blockIdx.x * blockDim.x + threadIdx.x;
    if (i < n4) {
        float4 v = reinterpret_cast<const float4*>(in)[i];
        f16x4 h; h[0] = (f16)v.x; h[1] = (f16)v.y; h[2] = (f16)v.z; h[3] = (f16)v.w;
        reinterpret_cast<f16x4*>(out)[i] = h;
    }
}

// ---------------- transpose + cast: in fp32 [R][C] -> out f16 [C][R] ----------------
__global__ void transpose_cast(const float* __restrict__ in, f16* __restrict__ out, int R, int C) {
    __shared__ float tile[32][33];
    int c0 = blockIdx.x * 32, r0 = blockIdx.y * 32;
    int tx = threadIdx.x & 31, ty = threadIdx.x >> 5;   // 32 x 8
#pragma unroll
    for (int j = 0; j < 4; j++)
        tile[ty + 8*j][tx] = in[(size_t)(r0 + ty + 8*j) * C + c0 + tx];
    __syncthreads();
#pragma unroll
    for (int j = 0; j < 4; j++)
        out[(size_t)(c0 + ty + 8*j) * R + r0 + tx] = (f16)tile[tx][ty + 8*j];
}

// ---------------- f16 MFMA GEMM: C[M][N] = A[M][K] @ Bt[N][K]^T ----------------
// EPI 0: scatter q(f16, pre-scaled 0.125), k(f16 row-major), v(f16 TRANSPOSED per head)
// EPI 1: + bias, write fp32 to d_out
template<int EPI>
__launch_bounds__(256, 2)
__global__ void gemm_f16(const f16* __restrict__ A, const f16* __restrict__ Bt,
                         int M, int N, int K,
                         f16* __restrict__ q16, f16* __restrict__ k16,
                         f16* __restrict__ vt16,
                         const float* __restrict__ bias, float* __restrict__ outf) {
    __shared__ f16 As[128 * 40];   // 128 rows x 32 k, padded to 40 f16
    __shared__ f16 Bs[128 * 40];
    int tid  = threadIdx.x;
    int lane = tid & 63, w = tid >> 6;
    int wm = w >> 1, wn = w & 1;                 // 2x2 waves, each 64x64
    int l15 = lane & 15, l4 = lane >> 4;
    int mBase = blockIdx.y * 128, nBase = blockIdx.x * 128;
    int r0 = tid >> 2, s0 = tid & 3;             // staging: row, 8-f16 segment

    f32x4 acc[4][4] = {};

    const int KT = K / 32;
    for (int kt = 0; kt < KT; kt++) {
        int k0 = kt * 32;
        *(f16x8*)&As[r0*40 + s0*8]        = *(const f16x8*)&A [(size_t)(mBase + r0     ) * K + k0 + s0*8];
        *(f16x8*)&As[(r0+64)*40 + s0*8]   = *(const f16x8*)&A [(size_t)(mBase + r0 + 64) * K + k0 + s0*8];
        *(f16x8*)&Bs[r0*40 + s0*8]        = *(const f16x8*)&Bt[(size_t)(nBase + r0     ) * K + k0 + s0*8];
        *(f16x8*)&Bs[(r0+64)*40 + s0*8]   = *(const f16x8*)&Bt[(size_t)(nBase + r0 + 64) * K + k0 + s0*8];
        __syncthreads();
        f16x8 af[4], bf[4];
#pragma unroll
        for (int i = 0; i < 4; i++) {
            af[i] = *(const f16x8*)&As[(wm*64 + i*16 + l15)*40 + l4*8];
            bf[i] = *(const f16x8*)&Bs[(wn*64 + i*16 + l15)*40 + l4*8];
        }
#pragma unroll
        for (int i = 0; i < 4; i++)
#pragma unroll
            for (int j = 0; j < 4; j++)
                acc[i][j] = __builtin_amdgcn_mfma_f32_16x16x32_f16(af[i], bf[j], acc[i][j], 0, 0, 0);
        __syncthreads();
    }

    int rbase2 = mBase + wm*64;
    int cbase2 = nBase + wn*64;
#pragma unroll
    for (int i = 0; i < 4; i++) {
#pragma unroll
        for (int j = 0; j < 4; j++) {
            int col = cbase2 + j*16 + l15;
#pragma unroll
            for (int r = 0; r < 4; r++) {
                int row = rbase2 + i*16 + l4*4 + r;
                float val = acc[i][j][r];
                if constexpr (EPI == 0) {
                    if (col < 768) {
                        q16[(size_t)row * 768 + col] = (f16)(val * 0.125f);  // fold attn SCALE
                    } else {
                        int n = row / QPN; int rem = row - n*QPN;
                        int t = rem / SS;  int s   = rem - t*SS;
                        if (!(s & 1)) {
                            int kb = t*(SS/2) + (s >> 1);                    // key idx within batch
                            if (col < 1536) {
                                k16[(size_t)(n*KPN + kb) * 768 + (col - 768)] = (f16)val;
                            } else {
                                int c = col - 1536; int hh = c >> 6, dd = c & 63;
                                vt16[((size_t)(n*NHEADS + hh)*64 + dd) * KPN + kb] = (f16)val;
                            }
                        }
                    }
                } else {
                    outf[(size_t)row * 768 + col] = val + bias[col];
                }
            }
        }
    }
}

// ---------------- MFMA flash attention (16x16x32, KVBLK=64 + 32-key tail) ----------
// Block: 256 thr = 4 waves, each wave owns 16 q-rows. Grid (49, 24).
// LDS rows LSTR=72 f16 = 144B: 16B-aligned (b128-safe) and bank rotation 4r mod 32
// -> optimal 2-way cover for 16-row b128 phases. Swapped QK^T: S[key][q]; P via
// per-wave LDS round-trip; PV: O[d][q] = mfma(Vt, P). Defer-max (T13, THR=8).
__launch_bounds__(256, 2)
__global__ void attn_mfma(const f16* __restrict__ q16, const f16* __restrict__ k16,
                          const f16* __restrict__ vt16, f16* __restrict__ o16) {
    int tid = threadIdx.x;
    int lane = tid & 63, w = tid >> 6;
    int qt = blockIdx.x, nh = blockIdx.y;
    int n = nh / NHEADS, h = nh - n*NHEADS;
    int l15 = lane & 15, l4 = lane >> 4;

    __shared__ f16 Klds[64 * LSTR];       // 64 keys x 64 d
    __shared__ f16 Vtlds[64 * LSTR];      // 64 d x 64 keys
    __shared__ f16 Plds[4][16 * LSTR];    // per-wave: 16 q x 64 keys

    // main staging: rows srow and srow+32, 8 segs of 8 f16 (16B) per row
    int srow = tid >> 3, sseg = tid & 7;
    const f16* kgb = k16 + (size_t)n * KPN * 768 + h * 64;
    const f16* vgb = vt16 + ((size_t)nh * 64 + srow) * KPN;   // V^T row d=srow
    // tail staging coords (V: 64 rows x 32 keys)
    int tvd = tid >> 2, tvs = tid & 3;
    const f16* vgb_tail = vt16 + ((size_t)nh * 64 + tvd) * KPN;

    int qglob = n*QPN + qt*64 + w*16 + l15;
    const f16* qrow = q16 + (size_t)qglob * 768 + h*64;
    f16x8 qf0 = *(const f16x8*)&qrow[l4*8];        // B-frag: col=q=l15, k=d=l4*8+i
    f16x8 qf1 = *(const f16x8*)&qrow[32 + l4*8];   // d = 32+l4*8+i

    f32x4 acc[4] = {};                  // acc[c][r] -> O[d=c*16+l4*4+r][q=l15]
    float M = -INFINITY, L = 0.f;

    // preload tile 0
    f16x8 stKa = *(const f16x8*)&kgb[(size_t)srow * 768 + sseg*8];
    f16x8 stKb = *(const f16x8*)&kgb[(size_t)(srow+32) * 768 + sseg*8];
    f16x8 stVa = *(const f16x8*)&vgb[sseg*8];
    f16x8 stVb = *(const f16x8*)&vgb[(size_t)32*KPN + sseg*8];

    for (int t = 0; t < 24; t++) {
        __syncthreads();   // prev tile reads done
        *(f16x8*)&Klds [srow*LSTR + sseg*8]      = stKa;
        *(f16x8*)&Klds [(srow+32)*LSTR + sseg*8] = stKb;
        *(f16x8*)&Vtlds[srow*LSTR + sseg*8]      = stVa;
        *(f16x8*)&Vtlds[(srow+32)*LSTR + sseg*8] = stVb;
        __syncthreads();   // tile t visible

        if (t < 23) {      // prefetch next 64-key tile
            int kb = (t + 1) * 64;
            stKa = *(const f16x8*)&kgb[(size_t)(kb + srow) * 768 + sseg*8];
            stKb = *(const f16x8*)&kgb[(size_t)(kb + srow + 32) * 768 + sseg*8];
            stVa = *(const f16x8*)&vgb[kb + sseg*8];
            stVb = *(const f16x8*)&vgb[(size_t)32*KPN + kb + sseg*8];
        } else {           // prefetch 32-key tail
            stKa = *(const f16x8*)&kgb[(size_t)(1536 + srow) * 768 + sseg*8];
            stVa = *(const f16x8*)&vgb_tail[1536 + tvs*8];
        }

        // ---- QK^T: S[kh][r] = S[key = kh*16+l4*4+r][q = l15]
        f32x4 S[4];
#pragma unroll
        for (int kh = 0; kh < 4; kh++) {
            const f16* kr = &Klds[(kh*16 + l15)*LSTR];
            f16x8 ka0 = *(const f16x8*)&kr[l4*8];
            f16x8 ka1 = *(const f16x8*)&kr[32 + l4*8];
            f32x4 s = {};
            s = __builtin_amdgcn_mfma_f32_16x16x32_f16(ka0, qf0, s, 0, 0, 0);
            s = __builtin_amdgcn_mfma_f32_16x16x32_f16(ka1, qf1, s, 0, 0, 0);
            S[kh] = s;
        }

        // ---- online softmax (q = l15; reduce over l4 group via shfl 16/32)
        float tm = -INFINITY;
#pragma unroll
        for (int kh = 0; kh < 4; kh++)
            tm = fmaxf(tm, fmaxf(fmaxf(S[kh][0], S[kh][1]), fmaxf(S[kh][2], S[kh][3])));
        tm = fmaxf(tm, __shfl_xor(tm, 16));
        tm = fmaxf(tm, __shfl_xor(tm, 32));
        if (!__all(tm - M <= 8.f)) {        // defer-max: rescale only on real growth
            float Mnew = fmaxf(M, tm);
            float cor = __expf(M - Mnew);   // first tile: exp(-inf)=0
            L *= cor;
#pragma unroll
            for (int c = 0; c < 4; c++) acc[c] *= cor;
            M = Mnew;
        }
        float ls = 0.f;
        f16* pw = &Plds[w][l15*LSTR];
#pragma unroll
        for (int kh = 0; kh < 4; kh++) {
            float p0 = __expf(S[kh][0] - M), p1 = __expf(S[kh][1] - M);
            float p2 = __expf(S[kh][2] - M), p3 = __expf(S[kh][3] - M);
            ls += (p0 + p1) + (p2 + p3);
            uint2 pk2; pk2.x = pk16(p0, p1); pk2.y = pk16(p2, p3);
            *(uint2*)&pw[kh*16 + l4*4] = pk2;     // keys kh*16 + l4*4 + 0..3
        }
        ls += __shfl_xor(ls, 16);
        ls += __shfl_xor(ls, 32);
        L += ls;

        // ---- PV: O[d][q] += Vt[d][k] * P[q][k], two 32-key slices
#pragma unroll
        for (int ks = 0; ks < 2; ks++) {
            f16x8 pf = *(const f16x8*)&Plds[w][l15*LSTR + ks*32 + l4*8];
#pragma unroll
            for (int c = 0; c < 4; c++) {
                f16x8 vf = *(const f16x8*)&Vtlds[(c*16 + l15)*LSTR + ks*32 + l4*8];
                acc[c] = __builtin_amdgcn_mfma_f32_16x16x32_f16(vf, pf, acc[c], 0, 0, 0);
            }
        }
    }

    // ---- tail: 32 keys at kb=1536 ----
    __syncthreads();
    *(f16x8*)&Klds [srow*LSTR + sseg*8] = stKa;    // 32 key-rows
    *(f16x8*)&Vtlds[tvd*LSTR + tvs*8]   = stVa;    // 64 d-rows x 32 keys
    __syncthreads();
    {
        f32x4 S[2];
#pragma unroll
        for (int kh = 0; kh < 2; kh++) {
            const f16* kr = &Klds[(kh*16 + l15)*LSTR];
            f16x8 ka0 = *(const f16x8*)&kr[l4*8];
            f16x8 ka1 = *(const f16x8*)&kr[32 + l4*8];
            f32x4 s = {};
            s = __builtin_amdgcn_mfma_f32_16x16x32_f16(ka0, qf0, s, 0, 0, 0);
            s = __builtin_amdgcn_mfma_f32_16x16x32_f16(ka1, qf1, s, 0, 0, 0);
            S[kh] = s;
        }
        float tm = -INFINITY;
#pragma unroll
        for (int kh = 0; kh < 2; kh++)
            tm = fmaxf(tm, fmaxf(fmaxf(S[kh][0], S[kh][1]), fmaxf(S[kh][2], S[kh][3])));
        tm = fmaxf(tm, __shfl_xor(tm, 16));
        tm = fmaxf(tm, __shfl_xor(tm, 32));
        if (!__all(tm - M <= 8.f)) {
            float Mnew = fmaxf(M, tm);
            float cor = __expf(M - Mnew);
            L *= cor;
#pragma unroll
            for (int c = 0; c < 4; c++) acc[c] *= cor;
            M = Mnew;
        }
        float ls = 0.f;
        f16* pw = &Plds[w][l15*LSTR];
#pragma unroll
        for (int kh = 0; kh < 2; kh++) {
            float p0 = __expf(S[kh][0] - M), p1 = __expf(S[kh][1] - M);
            float p2 = __expf(S[kh][2] - M), p3 = __expf(S[kh][3] - M);
            ls += (p0 + p1) + (p2 + p3);
            uint2 pk2; pk2.x = pk16(p0, p1); pk2.y = pk16(p2, p3);
            *(uint2*)&pw[kh*16 + l4*4] = pk2;
        }
        ls += __shfl_xor(ls, 16);
        ls += __shfl_xor(ls, 32);
        L += ls;

        f16x8 pf = *(const f16x8*)&Plds[w][l15*LSTR + l4*8];
#pragma unroll
        for (int c = 0; c < 4; c++) {
            f16x8 vf = *(const f16x8*)&Vtlds[(c*16 + l15)*LSTR + l4*8];
            acc[c] = __builtin_amdgcn_mfma_f32_16x16x32_f16(vf, pf, acc[c], 0, 0, 0);
        }
    }

    // ---- epilogue: O[q][d] = acc / L
    float inv = 1.f / L;
    f16* orow = o16 + (size_t)qglob * 768 + h*64;
#pragma unroll
    for (int c = 0; c < 4; c++) {
        uint2 o2;
        o2.x = pk16(acc[c][0]*inv, acc[c][1]*inv);
        o2.y = pk16(acc[c][2]*inv, acc[c][3]*inv);
        *(uint2*)&orow[c*16 + l4*4] = o2;
    }
}

extern "C" void kernel_launch(void* const* d_in, const int* in_sizes, int n_in,
                              void* d_out, int out_size, void* d_ws, size_t ws_size,
                              hipStream_t stream) {
    const float* x      = (const float*)d_in[0];
    const float* W_qkv  = (const float*)d_in[1];
    const float* W_proj = (const float*)d_in[2];
    const float* b_proj = (const float*)d_in[3];
    float* out = (float*)d_out;

    char* ws = (char*)d_ws;
    size_t off = 0;
    auto alloc = [&](size_t bytes) { void* p = ws + off; off += (bytes + 255) & ~255ULL; return p; };
    f16* x16    = (f16*)alloc((size_t)TOK * DD * 2);
    f16* WqkvT  = (f16*)alloc((size_t)2304 * 768 * 2);
    f16* WprojT = (f16*)alloc((size_t)768 * 768 * 2);
    f16* q16    = (f16*)alloc((size_t)TOK * DD * 2);
    f16* k16    = (f16*)alloc((size_t)NB * KPN * DD * 2);
    f16* vt16   = (f16*)alloc((size_t)NB * NHEADS * HD * KPN * 2);
    f16* o16    = (f16*)alloc((size_t)TOK * DD * 2);
    (void)ws_size; (void)in_sizes; (void)n_in; (void)out_size;

    cast_f32_to_f16<<<(TOK*DD/4 + 255)/256, 256, 0, stream>>>(x, x16, TOK*DD/4);
    transpose_cast<<<dim3(2304/32, 768/32), 256, 0, stream>>>(W_qkv, WqkvT, 768, 2304);
    transpose_cast<<<dim3(768/32, 768/32), 256, 0, stream>>>(W_proj, WprojT, 768, 768);
    gemm_f16<0><<<dim3(2304/128, 6272/128), 256, 0, stream>>>(
        x16, WqkvT, TOK, 2304, 768, q16, k16, vt16, nullptr, nullptr);
    attn_mfma<<<dim3(49, 24), 256, 0, stream>>>(q16, k16, vt16, o16);
    gemm_f16<1><<<dim3(768/128, 6272/128), 256, 0, stream>>>(
        o16, WprojT, TOK, 768, 768, nullptr, nullptr, nullptr, b_proj, out);
}